// Round 8
// baseline (918.181 us; speedup 1.0000x reference)
//
#include <hip/hip_runtime.h>

#define N_NODES 100000
#define N_EDGES 1600000
#define IN_CH   64
#define HID_CH  64
#define OUT_CH  128

typedef __attribute__((ext_vector_type(8))) __bf16    bf16x8;
typedef __attribute__((ext_vector_type(4))) float     f32x4;
typedef __attribute__((ext_vector_type(2))) _Float16  f16x2;
typedef __attribute__((ext_vector_type(8))) _Float16  f16x8;

// ---- workspace byte offsets (total ~51.7 MB) ----
#define OFF_HSUM   0            // 100000*64*2  = 12,800,000 (f16 pairs, natural order)
#define OFF_XB     12800000     // 100000*64*2  = 12,800,000 (bf16 bits)
#define OFF_Z      25600000     // 100000*128*2 = 25,600,000 (f16: [0:64]=dst-half, [64:128]=src-half)
#define OFF_CNT    51200000     // 100000*4
#define OFF_NTYPE  51600000     // 100000*1

__device__ __forceinline__ unsigned short f2bf(float f) {
    union { float f; unsigned int i; } c;
    c.f = f;
    unsigned int u = c.i;
    unsigned int r = (u + 0x7FFFu + ((u >> 16) & 1u)) >> 16;   // RNE
    return (unsigned short)r;
}

// packed fp16 atomic add (global_atomic_pk_add_f16, gfx90a+)
__device__ __forceinline__ void atomic_pk_add_f16(unsigned int* addr, f16x2 val) {
    typedef __attribute__((address_space(1))) f16x2 gf16x2;
    __builtin_amdgcn_global_atomic_fadd_v2f16((gf16x2*)(void*)addr, val);
}

// prep: x fp32->bf16 + node-type byte table + zero hsum/cnt (r0-proven).
__global__ void gnn_prep(const float* __restrict__ xf,
                         unsigned short* __restrict__ xb,
                         unsigned char* __restrict__ ntype,
                         uint4* __restrict__ hz,      // hsum as uint4 (800k)
                         float4* __restrict__ cz) {   // cnt  as float4 (25k)
    int i = blockIdx.x * blockDim.x + threadIdx.x;
    if (i < 1600000) {
        float4 v = reinterpret_cast<const float4*>(xf)[i];
        ushort4 o;
        o.x = f2bf(v.x); o.y = f2bf(v.y); o.z = f2bf(v.z); o.w = f2bf(v.w);
        reinterpret_cast<ushort4*>(xb)[i] = o;
        if ((i & 15) == 0) {
            int n = i >> 4;
            ntype[n] = (v.x == 0.0f) ? 0 : ((v.x == 1.0f) ? 1 : 2);
        }
    } else if (i < 2400000) {
        hz[i - 1600000] = (uint4){0u, 0u, 0u, 0u};
    } else if (i < 2425000) {
        cz[i - 2400000] = (float4){0.f, 0.f, 0.f, 0.f};
    }
}

// zgemm: z[n][j] = sum_k x[n][k] * Bc[k][j], Bc[k][j<64]=W1[k][j] (dst half),
// Bc[k][j>=64]=W1[64+k][j-64] (src half). Dense sequential MFMA GEMM:
// M=100K, K=64, N=128. Moves ALL W1 matrix work out of the edge kernel.
__global__ __launch_bounds__(256, 4) void gnn_zgemm(
    const unsigned short* __restrict__ xb,   // [N_NODES][64] bf16 bits
    const float*          __restrict__ W1,   // [131][64]
    _Float16*             __restrict__ z)    // [N_NODES][128]
{
    __shared__ __align__(16) unsigned short BT[128][72];  // BT[j][k]=Bc[k][j]

    const int tid  = threadIdx.x;
    const int wave = tid >> 6;
    const int lane = tid & 63;
    const int q    = lane >> 4;
    const int m16  = lane & 15;

    for (int idx = tid; idx < 64 * 128; idx += 256) {
        int k = idx >> 7, j = idx & 127;
        BT[j][k] = f2bf(W1[(k + ((j >= 64) ? 64 : 0)) * 64 + (j & 63)]);
    }
    __syncthreads();

    const int nodeBase = (blockIdx.x * 4 + wave) * 32;
    if (nodeBase >= N_NODES) return;

    f32x4 acc[2][8];
#pragma unroll
    for (int mt = 0; mt < 2; ++mt)
#pragma unroll
        for (int nt = 0; nt < 8; ++nt)
            acc[mt][nt] = (f32x4){0.0f, 0.0f, 0.0f, 0.0f};

#pragma unroll
    for (int kc = 0; kc < 2; ++kc) {
        bf16x8 af[2];
#pragma unroll
        for (int mt = 0; mt < 2; ++mt) {
            int node = nodeBase + mt * 16 + m16;
            if (node >= N_NODES) node = N_NODES - 1;   // clamp; rows unused
            af[mt] = *reinterpret_cast<const bf16x8*>(
                xb + (size_t)node * IN_CH + kc * 32 + q * 8);
        }
#pragma unroll
        for (int nt = 0; nt < 8; ++nt) {
            bf16x8 bfr = *reinterpret_cast<const bf16x8*>(
                &BT[nt * 16 + m16][kc * 32 + q * 8]);
            acc[0][nt] = __builtin_amdgcn_mfma_f32_16x16x32_bf16(af[0], bfr, acc[0][nt], 0, 0, 0);
            acc[1][nt] = __builtin_amdgcn_mfma_f32_16x16x32_bf16(af[1], bfr, acc[1][nt], 0, 0, 0);
        }
    }

    // C-layout: row = q*4+r, col = nt*16+m16
#pragma unroll
    for (int mt = 0; mt < 2; ++mt) {
#pragma unroll
        for (int nt = 0; nt < 8; ++nt) {
            int col = nt * 16 + m16;
#pragma unroll
            for (int r = 0; r < 4; ++r) {
                int n = nodeBase + mt * 16 + q * 4 + r;
                if (n < N_NODES)
                    z[(size_t)n * 128 + col] = (_Float16)acc[mt][nt][r];
            }
        }
    }
}

// edge_lite: per edge, h = relu(z[dst][0:64] + z[src][64:128] + ea@W1_tail + b1),
// packed-f16 atomics into hsum[dst]. NO MFMA, NO accumulator, NO edge staging:
// low VGPR, 1KB LDS -> max occupancy. Rounds 0-6 showed the edge phase is
// latency-bound (dur 154-172us invariant across 10x traffic; all pipes <18%):
// this kernel attacks it with more resident waves and 4 independent 16B
// gathers/lane. 4 lanes per edge (16 channels each); masked-out edges
// exec-mask out before gathering.
// launch_bounds (256,4): allocator free up to 128 VGPR (no forced spill —
// round-1 lesson); body is sized to land <=64 so HW still runs 8 waves/SIMD.
__global__ __launch_bounds__(256, 4) void gnn_edge_lite(
    const int*           __restrict__ eidx,  // [2][N_EDGES]
    const float*         __restrict__ ea,    // [N_EDGES][3]
    const unsigned char* __restrict__ ntype, // [N_NODES]
    const _Float16*      __restrict__ z,     // [N_NODES][128]
    const float*         __restrict__ W1,    // [131][64]
    const float*         __restrict__ b1,    // [64]
    unsigned int*        __restrict__ hsum,  // [N_NODES][32] f16 pairs
    float*               __restrict__ cnt)   // [N_NODES]
{
    __shared__ __align__(16) float tail[64][4];  // {W1[128][ch],W1[129][ch],W1[130][ch],b1[ch]}
    const int tid = threadIdx.x;
    if (tid < 64) {
        float4 tl;
        tl.x = W1[128 * 64 + tid];
        tl.y = W1[129 * 64 + tid];
        tl.z = W1[130 * 64 + tid];
        tl.w = b1[tid];
        *reinterpret_cast<float4*>(tail[tid]) = tl;
    }
    __syncthreads();

    const int gid    = blockIdx.x * 256 + tid;
    const int p      = gid & 3;                      // channel part 0..3
    const int stride = (gridDim.x * 256) >> 2;

    for (int e = gid >> 2; e < N_EDGES; e += stride) {
        int   s  = eidx[e];
        float a0 = ea[e * 3 + 0];
        int ntc = ntype[s];
        bool mk = (ntc == 0) ? (a0 < 0.5f) : ((ntc == 1) ? (a0 < 0.3f) : true);
        if (!mk) continue;                           // exec-mask: no gathers

        int   d  = eidx[N_EDGES + e];
        float a1 = ea[e * 3 + 1];
        float a2 = ea[e * 3 + 2];
        if (p == 0) unsafeAtomicAdd(&cnt[d], 1.0f);

        // gather this lane's 16-channel slices (4 lanes cover 128B contiguous)
        const _Float16* zdp = z + (size_t)d * 128 + p * 16;
        const _Float16* zsp = z + (size_t)s * 128 + 64 + p * 16;
        f16x8 zd0 = *reinterpret_cast<const f16x8*>(zdp);
        f16x8 zd1 = *reinterpret_cast<const f16x8*>(zdp + 8);
        f16x8 zs0 = *reinterpret_cast<const f16x8*>(zsp);
        f16x8 zs1 = *reinterpret_cast<const f16x8*>(zsp + 8);

        unsigned int* hb = hsum + (size_t)d * 32 + p * 8;
#pragma unroll
        for (int half = 0; half < 2; ++half) {
            f16x8 zd = half ? zd1 : zd0;
            f16x8 zs = half ? zs1 : zs0;
#pragma unroll
            for (int jj = 0; jj < 4; ++jj) {
                int ch = p * 16 + half * 8 + 2 * jj;
                float4 wA = *reinterpret_cast<const float4*>(tail[ch]);     // 16-way bcast
                float4 wB = *reinterpret_cast<const float4*>(tail[ch + 1]);
                float h0 = (float)zd[2 * jj]     + (float)zs[2 * jj]
                         + wA.w + a0 * wA.x + a1 * wA.y + a2 * wA.z;
                float h1 = (float)zd[2 * jj + 1] + (float)zs[2 * jj + 1]
                         + wB.w + a0 * wB.x + a1 * wB.y + a2 * wB.z;
                h0 = h0 > 0.f ? h0 : 0.f;
                h1 = h1 > 0.f ? h1 : 0.f;
                if (h0 + h1 > 0.f) {                 // zero-skip
                    f16x2 pk = {(_Float16)h0, (_Float16)h1};
                    atomic_pk_add_f16(hb + half * 4 + jj, pk);
                }
            }
        }
    }
}

// Node kernel (MFMA): out[n] = relu(hsum[n] @ W2 + cnt[n]*b2). (r5-verified)
__global__ __launch_bounds__(256, 4) void gnn_node_out(
    const _Float16* __restrict__ hsum,  // [N_NODES][64] f16, natural order
    const float*    __restrict__ cnt,   // [N_NODES]
    const float*    __restrict__ W2,    // [64][128]
    const float*    __restrict__ b2,    // [128]
    float*          __restrict__ out)   // [N_NODES][128]
{
    __shared__ __align__(16) unsigned short W2T[128][72];  // W2T[n][k]=W2[k][n]
    __shared__ float b2s[128];

    const int tid  = threadIdx.x;
    const int wave = tid >> 6;
    const int lane = tid & 63;
    const int q    = lane >> 4;
    const int m16  = lane & 15;

    const int nodeBase = (blockIdx.x * 4 + wave) * 32;

    // prefetch this wave's hsum rows + cnt before LDS staging (hide HBM latency)
    f16x8 hpre[2][2];
    float cc[2][4];
#pragma unroll
    for (int kc = 0; kc < 2; ++kc)
#pragma unroll
        for (int mt = 0; mt < 2; ++mt) {
            int node = nodeBase + mt * 16 + m16;
            if (node >= N_NODES) node = N_NODES - 1;
            hpre[kc][mt] = *reinterpret_cast<const f16x8*>(
                hsum + (size_t)node * HID_CH + kc * 32 + q * 8);
        }
#pragma unroll
    for (int mt = 0; mt < 2; ++mt)
#pragma unroll
        for (int r = 0; r < 4; ++r) {
            int n = nodeBase + mt * 16 + q * 4 + r;
            cc[mt][r] = (n < N_NODES) ? cnt[n] : 0.0f;
        }

    for (int idx = tid; idx < 64 * 128; idx += 256) {
        int k = idx >> 7, n = idx & 127;
        W2T[n][k] = f2bf(W2[k * 128 + n]);
    }
    if (tid < 128) b2s[tid] = b2[tid];
    __syncthreads();

    if (nodeBase >= N_NODES) return;

    f32x4 acc[2][8];
#pragma unroll
    for (int mt = 0; mt < 2; ++mt)
#pragma unroll
        for (int nt = 0; nt < 8; ++nt)
            acc[mt][nt] = (f32x4){0.0f, 0.0f, 0.0f, 0.0f};

#pragma unroll
    for (int kc = 0; kc < 2; ++kc) {
        bf16x8 af[2];
#pragma unroll
        for (int mt = 0; mt < 2; ++mt) {
            union { bf16x8 v; unsigned short u[8]; } rr;
#pragma unroll
            for (int j = 0; j < 8; ++j) rr.u[j] = f2bf((float)hpre[kc][mt][j]);
            af[mt] = rr.v;
        }
#pragma unroll
        for (int nt = 0; nt < 8; ++nt) {
            bf16x8 bfr = *reinterpret_cast<const bf16x8*>(
                &W2T[nt * 16 + m16][kc * 32 + q * 8]);
            acc[0][nt] = __builtin_amdgcn_mfma_f32_16x16x32_bf16(af[0], bfr, acc[0][nt], 0, 0, 0);
            acc[1][nt] = __builtin_amdgcn_mfma_f32_16x16x32_bf16(af[1], bfr, acc[1][nt], 0, 0, 0);
        }
    }

#pragma unroll
    for (int mt = 0; mt < 2; ++mt) {
        int nn[4];
#pragma unroll
        for (int r = 0; r < 4; ++r)
            nn[r] = nodeBase + mt * 16 + q * 4 + r;
#pragma unroll
        for (int nt = 0; nt < 8; ++nt) {
            int col = nt * 16 + m16;
            float bb = b2s[col];
#pragma unroll
            for (int r = 0; r < 4; ++r) {
                if (nn[r] < N_NODES) {
                    float v = acc[mt][nt][r] + cc[mt][r] * bb;
                    out[(size_t)nn[r] * OUT_CH + col] = v > 0.0f ? v : 0.0f;
                }
            }
        }
    }
}

extern "C" void kernel_launch(void* const* d_in, const int* in_sizes, int n_in,
                              void* d_out, int out_size, void* d_ws, size_t ws_size,
                              hipStream_t stream) {
    const float* x  = (const float*)d_in[0];
    const int*   ei = (const int*)d_in[1];
    const float* ea = (const float*)d_in[2];
    const float* W1 = (const float*)d_in[3];
    const float* b1 = (const float*)d_in[4];
    const float* W2 = (const float*)d_in[5];
    const float* b2 = (const float*)d_in[6];
    float* out = (float*)d_out;

    char* wsb = (char*)d_ws;
    unsigned int*   hsum  = (unsigned int*)  (wsb + OFF_HSUM);
    unsigned short* xb    = (unsigned short*)(wsb + OFF_XB);
    _Float16*       z     = (_Float16*)      (wsb + OFF_Z);
    float*          cnt   = (float*)         (wsb + OFF_CNT);
    unsigned char*  ntype = (unsigned char*) (wsb + OFF_NTYPE);

    // prep: x->bf16 + ntype + zero hsum/cnt
    gnn_prep<<<(2425000 + 255) / 256, 256, 0, stream>>>(
        x, xb, ntype, (uint4*)hsum, (float4*)cnt);

    // node-level W1 pre-GEMM: z = x @ [W1_dst | W1_src]  (M=100K,K=64,N=128)
    gnn_zgemm<<<(N_NODES + 127) / 128, 256, 0, stream>>>(xb, W1, z);

    // edge phase: pure gather+VALU+packed-f16 atomics, max occupancy
    gnn_edge_lite<<<2048, 256, 0, stream>>>(ei, ea, ntype, z, W1, b1, hsum, cnt);

    // node-level layer 2 + relu via MFMA
    gnn_node_out<<<(N_NODES + 127) / 128, 256, 0, stream>>>(
        (const _Float16*)hsum, cnt, W2, b2, out);
}

// Round 9
// 297.911 us; speedup vs baseline: 3.0821x; 3.0821x over previous
//
#include <hip/hip_runtime.h>

#define N_NODES 100000
#define N_EDGES 1600000
#define IN_CH   64
#define HID_CH  64
#define OUT_CH  128

typedef __attribute__((ext_vector_type(8))) __bf16    bf16x8;
typedef __attribute__((ext_vector_type(4))) float     f32x4;
typedef __attribute__((ext_vector_type(2))) _Float16  f16x2;
typedef __attribute__((ext_vector_type(8))) _Float16  f16x8;

// ---- workspace byte offsets (total ~51.7 MB) ----
#define OFF_HSUM   0            // 100000*64*2  = 12,800,000 (f16 pairs, natural order)
#define OFF_XB     12800000     // 100000*64*2  = 12,800,000 (bf16 bits)
#define OFF_Z      25600000     // 100000*128*2 = 25,600,000 (f16: [0:64]=dst-half, [64:128]=src-half)
#define OFF_CNT    51200000     // 100000*4
#define OFF_NTYPE  51600000     // 100000*1

__device__ __forceinline__ unsigned short f2bf(float f) {
    union { float f; unsigned int i; } c;
    c.f = f;
    unsigned int u = c.i;
    unsigned int r = (u + 0x7FFFu + ((u >> 16) & 1u)) >> 16;   // RNE
    return (unsigned short)r;
}

// packed fp16 atomic add (global_atomic_pk_add_f16, gfx90a+)
__device__ __forceinline__ void atomic_pk_add_f16(unsigned int* addr, f16x2 val) {
    typedef __attribute__((address_space(1))) f16x2 gf16x2;
    __builtin_amdgcn_global_atomic_fadd_v2f16((gf16x2*)(void*)addr, val);
}

// prep: x fp32->bf16 + node-type byte table + zero hsum/cnt (r0-proven).
__global__ void gnn_prep(const float* __restrict__ xf,
                         unsigned short* __restrict__ xb,
                         unsigned char* __restrict__ ntype,
                         uint4* __restrict__ hz,      // hsum as uint4 (800k)
                         float4* __restrict__ cz) {   // cnt  as float4 (25k)
    int i = blockIdx.x * blockDim.x + threadIdx.x;
    if (i < 1600000) {
        float4 v = reinterpret_cast<const float4*>(xf)[i];
        ushort4 o;
        o.x = f2bf(v.x); o.y = f2bf(v.y); o.z = f2bf(v.z); o.w = f2bf(v.w);
        reinterpret_cast<ushort4*>(xb)[i] = o;
        if ((i & 15) == 0) {
            int n = i >> 4;
            ntype[n] = (v.x == 0.0f) ? 0 : ((v.x == 1.0f) ? 1 : 2);
        }
    } else if (i < 2400000) {
        hz[i - 1600000] = (uint4){0u, 0u, 0u, 0u};
    } else if (i < 2425000) {
        cz[i - 2400000] = (float4){0.f, 0.f, 0.f, 0.f};
    }
}

// zgemm: z[n][j] = sum_k x[n][k] * Bc[k][j], Bc[k][j<64]=W1[k][j] (dst half),
// Bc[k][j>=64]=W1[64+k][j-64] (src half). Dense sequential MFMA GEMM.
__global__ __launch_bounds__(256, 4) void gnn_zgemm(
    const unsigned short* __restrict__ xb,   // [N_NODES][64] bf16 bits
    const float*          __restrict__ W1,   // [131][64]
    _Float16*             __restrict__ z)    // [N_NODES][128]
{
    __shared__ __align__(16) unsigned short BT[128][72];  // BT[j][k]=Bc[k][j]

    const int tid  = threadIdx.x;
    const int wave = tid >> 6;
    const int lane = tid & 63;
    const int q    = lane >> 4;
    const int m16  = lane & 15;

    for (int idx = tid; idx < 64 * 128; idx += 256) {
        int k = idx >> 7, j = idx & 127;
        BT[j][k] = f2bf(W1[(k + ((j >= 64) ? 64 : 0)) * 64 + (j & 63)]);
    }
    __syncthreads();

    const int nodeBase = (blockIdx.x * 4 + wave) * 32;
    if (nodeBase >= N_NODES) return;

    f32x4 acc[2][8];
#pragma unroll
    for (int mt = 0; mt < 2; ++mt)
#pragma unroll
        for (int nt = 0; nt < 8; ++nt)
            acc[mt][nt] = (f32x4){0.0f, 0.0f, 0.0f, 0.0f};

#pragma unroll
    for (int kc = 0; kc < 2; ++kc) {
        bf16x8 af[2];
#pragma unroll
        for (int mt = 0; mt < 2; ++mt) {
            int node = nodeBase + mt * 16 + m16;
            if (node >= N_NODES) node = N_NODES - 1;   // clamp; rows unused
            af[mt] = *reinterpret_cast<const bf16x8*>(
                xb + (size_t)node * IN_CH + kc * 32 + q * 8);
        }
#pragma unroll
        for (int nt = 0; nt < 8; ++nt) {
            bf16x8 bfr = *reinterpret_cast<const bf16x8*>(
                &BT[nt * 16 + m16][kc * 32 + q * 8]);
            acc[0][nt] = __builtin_amdgcn_mfma_f32_16x16x32_bf16(af[0], bfr, acc[0][nt], 0, 0, 0);
            acc[1][nt] = __builtin_amdgcn_mfma_f32_16x16x32_bf16(af[1], bfr, acc[1][nt], 0, 0, 0);
        }
    }

    // C-layout: row = q*4+r, col = nt*16+m16
#pragma unroll
    for (int mt = 0; mt < 2; ++mt) {
#pragma unroll
        for (int nt = 0; nt < 8; ++nt) {
            int col = nt * 16 + m16;
#pragma unroll
            for (int r = 0; r < 4; ++r) {
                int n = nodeBase + mt * 16 + q * 4 + r;
                if (n < N_NODES)
                    z[(size_t)n * 128 + col] = (_Float16)acc[mt][nt][r];
            }
        }
    }
}

// edge_quad: one QUAD (16 lanes) per edge. Lane m16 owns channels
// (2m16, 2m16+1) and (32+2m16, 33+2m16) -> the quad's two atomics cover
// dwords 0..15 and 16..31 of hsum[d]: 64B-contiguous per atomic instruction
// (r0's proven coalescing; r8's per-lane scatter caused 5x write
// amplification, WRITE 150->742MB). Gathers: the quad's f16x2 loads span
// 64B-contiguous slices of z[d] / z[s] -> 4 lines per wave-instruction.
// No MFMA, no barriers, no LDS in the loop (weight tail in 16 regs ->
// kills r8's 40M LDS bank conflicts). High occupancy + 4 indep gathers/lane.
__global__ __launch_bounds__(256, 4) void gnn_edge_quad(
    const int*           __restrict__ eidx,  // [2][N_EDGES]
    const float*         __restrict__ ea,    // [N_EDGES][3]
    const unsigned char* __restrict__ ntype, // [N_NODES]
    const _Float16*      __restrict__ z,     // [N_NODES][128]
    const float*         __restrict__ W1,    // [131][64]
    const float*         __restrict__ b1,    // [64]
    unsigned int*        __restrict__ hsum,  // [N_NODES][32] f16 pairs (natural)
    float*               __restrict__ cnt)   // [N_NODES]
{
    const int tid  = threadIdx.x;
    const int lane = tid & 63;
    const int q    = lane >> 4;   // quad 0..3 = edge slot within wave
    const int m16  = lane & 15;

    // per-lane weight tail in registers: channels c0=2m16, c0+1, c0+32, c0+33
    const int c0 = 2 * m16;
    const float wx0 = W1[128 * 64 + c0],      wx1 = W1[128 * 64 + c0 + 1];
    const float wx2 = W1[128 * 64 + c0 + 32], wx3 = W1[128 * 64 + c0 + 33];
    const float wy0 = W1[129 * 64 + c0],      wy1 = W1[129 * 64 + c0 + 1];
    const float wy2 = W1[129 * 64 + c0 + 32], wy3 = W1[129 * 64 + c0 + 33];
    const float wz0 = W1[130 * 64 + c0],      wz1 = W1[130 * 64 + c0 + 1];
    const float wz2 = W1[130 * 64 + c0 + 32], wz3 = W1[130 * 64 + c0 + 33];
    const float bb0 = b1[c0],                 bb1 = b1[c0 + 1];
    const float bb2 = b1[c0 + 32],            bb3 = b1[c0 + 33];

    const int wid    = (blockIdx.x * 256 + tid) >> 6;   // global wave id
    const int nwaves = (gridDim.x * 256) >> 6;

    for (int e = wid * 4 + q; e < N_EDGES; e += nwaves * 4) {
        int   s  = eidx[e];
        float a0 = ea[e * 3 + 0];
        int ntc = ntype[s];
        bool mk = (ntc == 0) ? (a0 < 0.5f) : ((ntc == 1) ? (a0 < 0.3f) : true);
        if (!mk) continue;                    // exec-mask; no gathers issued

        int   d  = eidx[N_EDGES + e];
        float a1 = ea[e * 3 + 1];
        float a2 = ea[e * 3 + 2];

        // gathers: quad spans 64B-contiguous slices (4 lines/wave-instr)
        const _Float16* zd = z + (size_t)d * 128;        // dst half: ch 0..63
        const _Float16* zs = z + (size_t)s * 128 + 64;   // src half: ch 0..63
        f16x2 zd01 = *reinterpret_cast<const f16x2*>(zd + c0);        // ch c0,c0+1
        f16x2 zd23 = *reinterpret_cast<const f16x2*>(zd + c0 + 32);   // ch c0+32,c0+33
        f16x2 zs01 = *reinterpret_cast<const f16x2*>(zs + c0);
        f16x2 zs23 = *reinterpret_cast<const f16x2*>(zs + c0 + 32);

        float h0 = (float)zd01[0] + (float)zs01[0] + bb0 + a0 * wx0 + a1 * wy0 + a2 * wz0;
        float h1 = (float)zd01[1] + (float)zs01[1] + bb1 + a0 * wx1 + a1 * wy1 + a2 * wz1;
        float h2 = (float)zd23[0] + (float)zs23[0] + bb2 + a0 * wx2 + a1 * wy2 + a2 * wz2;
        float h3 = (float)zd23[1] + (float)zs23[1] + bb3 + a0 * wx3 + a1 * wy3 + a2 * wz3;
        h0 = h0 > 0.f ? h0 : 0.f;
        h1 = h1 > 0.f ? h1 : 0.f;
        h2 = h2 > 0.f ? h2 : 0.f;
        h3 = h3 > 0.f ? h3 : 0.f;

        unsigned int* hb = hsum + (size_t)d * 32;
        if (h0 + h1 > 0.f) {                  // dword m16: quad covers 0..15
            f16x2 pk = {(_Float16)h0, (_Float16)h1};
            atomic_pk_add_f16(hb + m16, pk);
        }
        if (h2 + h3 > 0.f) {                  // dword 16+m16: quad covers 16..31
            f16x2 pk = {(_Float16)h2, (_Float16)h3};
            atomic_pk_add_f16(hb + 16 + m16, pk);
        }
        if (m16 == 0) unsafeAtomicAdd(&cnt[d], 1.0f);
    }
}

// Node kernel (MFMA): out[n] = relu(hsum[n] @ W2 + cnt[n]*b2). (r5-verified)
__global__ __launch_bounds__(256, 4) void gnn_node_out(
    const _Float16* __restrict__ hsum,  // [N_NODES][64] f16, natural order
    const float*    __restrict__ cnt,   // [N_NODES]
    const float*    __restrict__ W2,    // [64][128]
    const float*    __restrict__ b2,    // [128]
    float*          __restrict__ out)   // [N_NODES][128]
{
    __shared__ __align__(16) unsigned short W2T[128][72];  // W2T[n][k]=W2[k][n]
    __shared__ float b2s[128];

    const int tid  = threadIdx.x;
    const int wave = tid >> 6;
    const int lane = tid & 63;
    const int q    = lane >> 4;
    const int m16  = lane & 15;

    const int nodeBase = (blockIdx.x * 4 + wave) * 32;

    // prefetch this wave's hsum rows + cnt before LDS staging (hide HBM latency)
    f16x8 hpre[2][2];
    float cc[2][4];
#pragma unroll
    for (int kc = 0; kc < 2; ++kc)
#pragma unroll
        for (int mt = 0; mt < 2; ++mt) {
            int node = nodeBase + mt * 16 + m16;
            if (node >= N_NODES) node = N_NODES - 1;
            hpre[kc][mt] = *reinterpret_cast<const f16x8*>(
                hsum + (size_t)node * HID_CH + kc * 32 + q * 8);
        }
#pragma unroll
    for (int mt = 0; mt < 2; ++mt)
#pragma unroll
        for (int r = 0; r < 4; ++r) {
            int n = nodeBase + mt * 16 + q * 4 + r;
            cc[mt][r] = (n < N_NODES) ? cnt[n] : 0.0f;
        }

    for (int idx = tid; idx < 64 * 128; idx += 256) {
        int k = idx >> 7, n = idx & 127;
        W2T[n][k] = f2bf(W2[k * 128 + n]);
    }
    if (tid < 128) b2s[tid] = b2[tid];
    __syncthreads();

    if (nodeBase >= N_NODES) return;

    f32x4 acc[2][8];
#pragma unroll
    for (int mt = 0; mt < 2; ++mt)
#pragma unroll
        for (int nt = 0; nt < 8; ++nt)
            acc[mt][nt] = (f32x4){0.0f, 0.0f, 0.0f, 0.0f};

#pragma unroll
    for (int kc = 0; kc < 2; ++kc) {
        bf16x8 af[2];
#pragma unroll
        for (int mt = 0; mt < 2; ++mt) {
            union { bf16x8 v; unsigned short u[8]; } rr;
#pragma unroll
            for (int j = 0; j < 8; ++j) rr.u[j] = f2bf((float)hpre[kc][mt][j]);
            af[mt] = rr.v;
        }
#pragma unroll
        for (int nt = 0; nt < 8; ++nt) {
            bf16x8 bfr = *reinterpret_cast<const bf16x8*>(
                &W2T[nt * 16 + m16][kc * 32 + q * 8]);
            acc[0][nt] = __builtin_amdgcn_mfma_f32_16x16x32_bf16(af[0], bfr, acc[0][nt], 0, 0, 0);
            acc[1][nt] = __builtin_amdgcn_mfma_f32_16x16x32_bf16(af[1], bfr, acc[1][nt], 0, 0, 0);
        }
    }

#pragma unroll
    for (int mt = 0; mt < 2; ++mt) {
        int nn[4];
#pragma unroll
        for (int r = 0; r < 4; ++r)
            nn[r] = nodeBase + mt * 16 + q * 4 + r;
#pragma unroll
        for (int nt = 0; nt < 8; ++nt) {
            int col = nt * 16 + m16;
            float bb = b2s[col];
#pragma unroll
            for (int r = 0; r < 4; ++r) {
                if (nn[r] < N_NODES) {
                    float v = acc[mt][nt][r] + cc[mt][r] * bb;
                    out[(size_t)nn[r] * OUT_CH + col] = v > 0.0f ? v : 0.0f;
                }
            }
        }
    }
}

extern "C" void kernel_launch(void* const* d_in, const int* in_sizes, int n_in,
                              void* d_out, int out_size, void* d_ws, size_t ws_size,
                              hipStream_t stream) {
    const float* x  = (const float*)d_in[0];
    const int*   ei = (const int*)d_in[1];
    const float* ea = (const float*)d_in[2];
    const float* W1 = (const float*)d_in[3];
    const float* b1 = (const float*)d_in[4];
    const float* W2 = (const float*)d_in[5];
    const float* b2 = (const float*)d_in[6];
    float* out = (float*)d_out;

    char* wsb = (char*)d_ws;
    unsigned int*   hsum  = (unsigned int*)  (wsb + OFF_HSUM);
    unsigned short* xb    = (unsigned short*)(wsb + OFF_XB);
    _Float16*       z     = (_Float16*)      (wsb + OFF_Z);
    float*          cnt   = (float*)         (wsb + OFF_CNT);
    unsigned char*  ntype = (unsigned char*) (wsb + OFF_NTYPE);

    // prep: x->bf16 + ntype + zero hsum/cnt
    gnn_prep<<<(2425000 + 255) / 256, 256, 0, stream>>>(
        x, xb, ntype, (uint4*)hsum, (float4*)cnt);

    // node-level W1 pre-GEMM: z = x @ [W1_dst | W1_src]  (M=100K,K=64,N=128)
    gnn_zgemm<<<(N_NODES + 127) / 128, 256, 0, stream>>>(xb, W1, z);

    // edge phase: quad-per-edge gather + coalesced packed-f16 atomics
    gnn_edge_quad<<<2048, 256, 0, stream>>>(ei, ea, ntype, z, W1, b1, hsum, cnt);

    // node-level layer 2 + relu via MFMA
    gnn_node_out<<<(N_NODES + 127) / 128, 256, 0, stream>>>(
        (const _Float16*)hsum, cnt, W2, b2, out);
}